// Round 4
// baseline (417.279 us; speedup 1.0000x reference)
//
#include <hip/hip_runtime.h>
#include <hip/hip_bf16.h>

typedef __attribute__((ext_vector_type(8))) short short8;
typedef __attribute__((ext_vector_type(4))) float f32x4;
typedef unsigned short ushort;

#define BB 128
#define HHH 16
#define WWW 48
#define DD 512
#define UU 512
#define ROWS_PER_B (HHH * WWW)      /* 768 */
#define MTOT (BB * ROWS_PER_B)      /* 98304 */

__device__ __forceinline__ ushort f2bf(float f) {
    unsigned int u = __float_as_uint(f);
    u += 0x7fffu + ((u >> 16) & 1u);          // round-to-nearest-even
    return (ushort)(u >> 16);
}

__device__ __forceinline__ void gload_lds16(const ushort* g, ushort* l) {
    __builtin_amdgcn_global_load_lds(
        (const __attribute__((address_space(1))) unsigned int*)(const void*)g,
        (__attribute__((address_space(3))) unsigned int*)(void*)l,
        16, 0, 0);
}

// ---------------- kernel 0: prep = pack W1 + dec_proj ----------------------
// blocks 0..63:   pack W1 (D,U) fp32 -> w1p[kc][u][s^(u&7)] bf16
//                 w1p flat: kc*32768 + u*64 + s'*8 + j = W1[kc*64+s*8+j][u]
// blocks 64..319: dproj[b][u] = dec[b]@W2[:,u] + W1_b[u] + W2_b[u]
__global__ __launch_bounds__(256) void prep_kernel(
        const float* __restrict__ w1, const float* __restrict__ dec,
        const float* __restrict__ w2, const float* __restrict__ w1b,
        const float* __restrict__ w2b,
        ushort* __restrict__ w1p, float* __restrict__ dproj) {
    const int t = threadIdx.x;
    if (blockIdx.x < 64) {
        __shared__ __align__(16) ushort tile[64 * 72];
        const int u0 = (blockIdx.x & 7) * 64;
        const int kc = blockIdx.x >> 3;
        const int ul = t & 63;
        const int db = t >> 6;
#pragma unroll
        for (int i = 0; i < 16; ++i) {
            const int d = db + i * 4;
            tile[ul * 72 + d] = f2bf(w1[(size_t)(kc * 64 + d) * UU + u0 + ul]);
        }
        __syncthreads();
        const int u = t >> 2;
        const int s = (t & 3) * 2;
        const int x = u & 7;
        short8 v0 = *(const short8*)&tile[u * 72 + s * 8];
        short8 v1 = *(const short8*)&tile[u * 72 + s * 8 + 8];
        *(short8*)&w1p[(size_t)kc * 32768 + (u0 + u) * 64 + (( s      ^ x)) * 8] = v0;
        *(short8*)&w1p[(size_t)kc * 32768 + (u0 + u) * 64 + (((s + 1) ^ x)) * 8] = v1;
    } else {
        const int g = blockIdx.x - 64;
        const int b = g >> 1;
        const int u = (g & 1) * 256 + t;
        float acc = 0.f;
#pragma unroll 8
        for (int d = 0; d < DD; ++d)
            acc += dec[b * DD + d] * w2[(size_t)d * UU + u];
        dproj[b * UU + u] = acc + w1b[u] + w2b[u];
    }
}

// ---------------- kernel 1: fused score GEMM -------------------------------
// score[m] = V_b + sum_u V_w[u] * tanh( enc[m]@W1[:,u] + dec_proj[b][u] )
// Block: 128 m-rows x 512 u, K-step 64, 8 waves = 2 mh x 4 uc.
// A and B both double-buffered in LDS (160 KB): ONE barrier per K-step.
__global__ __launch_bounds__(512, 2) void score_kernel(
        const float* __restrict__ enc, const ushort* __restrict__ w1p,
        const float* __restrict__ dproj, const float* __restrict__ vw,
        const float* __restrict__ vb, float* __restrict__ score) {
    __shared__ __align__(16) ushort Bb[2][UU * 64];    // 2 x 64 KB
    __shared__ __align__(16) ushort Ab[2][128 * 64];   // 2 x 16 KB -> 160 KB

    const int tid  = threadIdx.x;
    const int lane = tid & 63;
    const int wave = tid >> 6;
    const int mbase = blockIdx.x * 128;
    const int b = mbase / ROWS_PER_B;

    const int mh   = wave >> 2;              // 0..1 -> 64 rows each
    const int uc   = wave & 3;               // 0..3 -> 128 u each
    const int lrow = lane & 15;
    const int kgrp = lane >> 4;

    // A staging mapping: thread -> (row, 16 floats = 2 swizzled 8-elem chunks)
    const int ar  = tid >> 2;                // 0..127
    const int asp = (tid & 3) * 2;           // 0,2,4,6
    const float* abase = enc + (size_t)(mbase + ar) * DD + asp * 8;
    const int s0p = ( asp      ^ (ar & 7)) * 8;
    const int s1p = ((asp + 1) ^ (ar & 7)) * 8;

    f32x4 acc[4][8] = {};

    // ---- prologue: stage kc = 0 into buffer 0 ----
    {
        float4 a0 = ((const float4*)abase)[0];
        float4 a1 = ((const float4*)abase)[1];
        float4 a2 = ((const float4*)abase)[2];
        float4 a3 = ((const float4*)abase)[3];
        const ushort* bsrc = w1p + tid * 8;
#pragma unroll
        for (int i = 0; i < 8; ++i)
            gload_lds16(bsrc + i * 4096, &Bb[0][tid * 8 + i * 4096]);
        short8 w0, w1v;
        ushort* p0 = (ushort*)&w0; ushort* p1 = (ushort*)&w1v;
        p0[0]=f2bf(a0.x); p0[1]=f2bf(a0.y); p0[2]=f2bf(a0.z); p0[3]=f2bf(a0.w);
        p0[4]=f2bf(a1.x); p0[5]=f2bf(a1.y); p0[6]=f2bf(a1.z); p0[7]=f2bf(a1.w);
        p1[0]=f2bf(a2.x); p1[1]=f2bf(a2.y); p1[2]=f2bf(a2.z); p1[3]=f2bf(a2.w);
        p1[4]=f2bf(a3.x); p1[5]=f2bf(a3.y); p1[6]=f2bf(a3.z); p1[7]=f2bf(a3.w);
        *(short8*)&Ab[0][ar * 64 + s0p] = w0;
        *(short8*)&Ab[0][ar * 64 + s1p] = w1v;
    }

#pragma unroll
    for (int kc = 0; kc < 8; ++kc) {
        const int cur = kc & 1;
        __syncthreads();                     // buf[cur] fully staged & visible

        float4 a0, a1, a2, a3;
        if (kc < 7) {                        // issue next-tile loads early
            const float* asrc = abase + (kc + 1) * 64;
            a0 = ((const float4*)asrc)[0];
            a1 = ((const float4*)asrc)[1];
            a2 = ((const float4*)asrc)[2];
            a3 = ((const float4*)asrc)[3];
            const ushort* bsrc = w1p + (size_t)(kc + 1) * 32768 + tid * 8;
#pragma unroll
            for (int i = 0; i < 8; ++i)
                gload_lds16(bsrc + i * 4096, &Bb[cur ^ 1][tid * 8 + i * 4096]);
        }

        const ushort* Bc = &Bb[cur][0];
        const ushort* Ac = &Ab[cur][0];
#pragma unroll
        for (int kk = 0; kk < 2; ++kk) {
            const int sub = kk * 4 + kgrp;
            short8 afr[4], bfr[8];
#pragma unroll
            for (int ms = 0; ms < 4; ++ms) {
                const int r = mh * 64 + ms * 16 + lrow;
                afr[ms] = *(const short8*)&Ac[r * 64 + (sub ^ (r & 7)) * 8];
            }
#pragma unroll
            for (int uf = 0; uf < 8; ++uf) {
                const int u = uc * 128 + uf * 16 + lrow;
                bfr[uf] = *(const short8*)&Bc[u * 64 + (sub ^ (u & 7)) * 8];
            }
#pragma unroll
            for (int ms = 0; ms < 4; ++ms)
#pragma unroll
                for (int uf = 0; uf < 8; ++uf)
                    acc[ms][uf] = __builtin_amdgcn_mfma_f32_16x16x32_bf16(
                        afr[ms], bfr[uf], acc[ms][uf], 0, 0, 0);
        }

        if (kc < 7) {                        // convert + write A into buf^1
            short8 w0, w1v;
            ushort* p0 = (ushort*)&w0; ushort* p1 = (ushort*)&w1v;
            p0[0]=f2bf(a0.x); p0[1]=f2bf(a0.y); p0[2]=f2bf(a0.z); p0[3]=f2bf(a0.w);
            p0[4]=f2bf(a1.x); p0[5]=f2bf(a1.y); p0[6]=f2bf(a1.z); p0[7]=f2bf(a1.w);
            p1[0]=f2bf(a2.x); p1[1]=f2bf(a2.y); p1[2]=f2bf(a2.z); p1[3]=f2bf(a2.w);
            p1[4]=f2bf(a3.x); p1[5]=f2bf(a3.y); p1[6]=f2bf(a3.z); p1[7]=f2bf(a3.w);
            *(short8*)&Ab[cur ^ 1][ar * 64 + s0p] = w0;
            *(short8*)&Ab[cur ^ 1][ar * 64 + s1p] = w1v;
        }
    }

    // ---- epilogue: + dec_proj, tanh, dot V_w, reduce ----
    float part[4][4] = {};
#pragma unroll
    for (int uf = 0; uf < 8; ++uf) {
        const int u = uc * 128 + uf * 16 + lrow;
        const float cadd = dproj[b * UU + u];
        const float vwe  = vw[u];
#pragma unroll
        for (int ms = 0; ms < 4; ++ms)
#pragma unroll
            for (int j = 0; j < 4; ++j) {
                float x = acc[ms][uf][j] + cadd;
                x = fminf(fmaxf(x, -15.f), 15.f);
                float e = __expf(2.f * x);
                part[ms][j] += vwe * ((e - 1.f) / (e + 1.f));
            }
    }
#pragma unroll
    for (int off = 1; off < 16; off <<= 1)
#pragma unroll
        for (int ms = 0; ms < 4; ++ms)
#pragma unroll
            for (int j = 0; j < 4; ++j)
                part[ms][j] += __shfl_xor(part[ms][j], off, 64);

    float* scr = (float*)&Ab[0][0];          // 2 KB scratch (Ab[0] is free)
    if (lrow == 0) {
#pragma unroll
        for (int ms = 0; ms < 4; ++ms)
#pragma unroll
            for (int j = 0; j < 4; ++j)
                scr[uc * 128 + mh * 64 + ms * 16 + kgrp * 4 + j] = part[ms][j];
    }
    __syncthreads();
    if (tid < 128)
        score[mbase + tid] = scr[tid] + scr[128 + tid] + scr[256 + tid]
                           + scr[384 + tid] + vb[0];
}

// ---------------- kernel 2: fused softmax + context partial ----------------
// grid (2, B): block (half, b). Softmax over H per (b,w) in LDS, write attn
// for this half's 384 rows, then accumulate a 384-row context partial per
// row-phase r0 (4 partial slices per block -> 8 per b).
__global__ __launch_bounds__(512) void ctx_kernel(
        const float* __restrict__ score, const float* __restrict__ enc,
        float* __restrict__ attn, float* __restrict__ partial) {
    __shared__ float sl[ROWS_PER_B];
    __shared__ float al[ROWS_PER_B];
    const int half = blockIdx.x;
    const int b    = blockIdx.y;
    const int t    = threadIdx.x;

    for (int i = t; i < ROWS_PER_B; i += 512) sl[i] = score[b * ROWS_PER_B + i];
    __syncthreads();

    if (t < WWW) {
        float v[HHH];
        float m = -1e30f;
#pragma unroll
        for (int h = 0; h < HHH; ++h) { v[h] = sl[h * WWW + t]; m = fmaxf(m, v[h]); }
        float sum = 0.f;
#pragma unroll
        for (int h = 0; h < HHH; ++h) { v[h] = __expf(v[h] - m); sum += v[h]; }
        const float inv = 1.f / sum;
#pragma unroll
        for (int h = 0; h < HHH; ++h) al[h * WWW + t] = v[h] * inv;
    }
    __syncthreads();

    const int rb = half * 384;
    for (int i = t; i < 384; i += 512)
        attn[b * ROWS_PER_B + rb + i] = al[rb + i];

    const int r0 = t >> 7;                   // 0..3 row phase
    const int d4 = (t & 127) * 4;
    float4 acc = {0.f, 0.f, 0.f, 0.f};
    const float* ebase = enc + ((size_t)b * ROWS_PER_B + rb) * DD + d4;
#pragma unroll 8
    for (int i = 0; i < 96; ++i) {
        const int r = r0 + i * 4;
        const float a = al[rb + r];
        const float4 e = *(const float4*)(ebase + (size_t)r * DD);
        acc.x += a * e.x; acc.y += a * e.y; acc.z += a * e.z; acc.w += a * e.w;
    }
    // 8 partial slices per b: index = ((b*2 + half)*4 + r0)
    *(float4*)(partial + ((size_t)((b * 2 + half) * 4 + r0)) * DD + d4) = acc;
}

// ---------------- kernel 3: reduce 8 partials ------------------------------
__global__ void ctx_reduce_kernel(const float* __restrict__ partial,
                                  float* __restrict__ out) {
    const int q = blockIdx.x * 256 + threadIdx.x;    // 16384 quads
    const int b = q >> 7;
    const int d4 = (q & 127) * 4;
    float4 s = {0.f, 0.f, 0.f, 0.f};
#pragma unroll
    for (int j = 0; j < 8; ++j) {
        const float4 p = *(const float4*)(partial + ((size_t)(b * 8 + j)) * DD + d4);
        s.x += p.x; s.y += p.y; s.z += p.z; s.w += p.w;
    }
    *(float4*)(out + (size_t)b * DD + d4) = s;
}

extern "C" void kernel_launch(void* const* d_in, const int* in_sizes, int n_in,
                              void* d_out, int out_size, void* d_ws, size_t ws_size,
                              hipStream_t stream) {
    const float* dec = (const float*)d_in[0];
    const float* enc = (const float*)d_in[1];
    const float* w1w = (const float*)d_in[2];
    const float* w1b = (const float*)d_in[3];
    const float* w2w = (const float*)d_in[4];
    const float* w2b = (const float*)d_in[5];
    const float* vw  = (const float*)d_in[6];
    const float* vb  = (const float*)d_in[7];

    float* out = (float*)d_out;
    char* ws = (char*)d_ws;
    ushort* w1p    = (ushort*)(ws);                                 // 512 KB
    float* dproj   = (float*)(ws + 524288);                         // 256 KB
    float* score   = (float*)(ws + 524288 + 262144);                // 384 KB
    float* partial = (float*)(ws + 524288 + 262144 + 393216);       // 2 MB

    float* ctx  = out;                 // (B, D)     = 65536 floats
    float* attn = out + BB * DD;       // (B,H,W,1)  = 98304 floats

    prep_kernel<<<320, 256, 0, stream>>>(w1w, dec, w2w, w1b, w2b, w1p, dproj);
    score_kernel<<<MTOT / 128, 512, 0, stream>>>(enc, w1p, dproj, vw, vb, score);
    ctx_kernel<<<dim3(2, BB), 512, 0, stream>>>(score, enc, attn, partial);
    ctx_reduce_kernel<<<64, 256, 0, stream>>>(partial, ctx);
}

// Round 5
// 397.589 us; speedup vs baseline: 1.0495x; 1.0495x over previous
//
#include <hip/hip_runtime.h>
#include <hip/hip_bf16.h>

typedef __attribute__((ext_vector_type(8))) short short8;
typedef __attribute__((ext_vector_type(4))) float f32x4;
typedef unsigned short ushort;

#define BB 128
#define HHH 16
#define WWW 48
#define DD 512
#define UU 512
#define ROWS_PER_B (HHH * WWW)      /* 768 */
#define MTOT (BB * ROWS_PER_B)      /* 98304 */
#define BM 64
#define BN 256
#define BK 64

__device__ __forceinline__ ushort f2bf(float f) {      // round-half-up (1 ulp vs RNE)
    return (ushort)((__float_as_uint(f) + 0x8000u) >> 16);
}

__device__ __forceinline__ void gload_lds16(const ushort* g, ushort* l) {
    __builtin_amdgcn_global_load_lds(
        (const __attribute__((address_space(1))) unsigned int*)(const void*)g,
        (__attribute__((address_space(3))) unsigned int*)(void*)l,
        16, 0, 0);
}

// ---------------- kernel 0: prep = pack W1 + dec_proj ----------------------
// blocks 0..63:   pack W1 (D,U) fp32 -> w1p[kc][u][s^(u&7)] bf16
//                 w1p flat: kc*32768 + u*64 + s'*8 + j = W1[kc*64+s*8+j][u]
// blocks 64..319: dproj[b][u] = dec[b]@W2[:,u] + W1_b[u] + W2_b[u]
__global__ __launch_bounds__(256) void prep_kernel(
        const float* __restrict__ w1, const float* __restrict__ dec,
        const float* __restrict__ w2, const float* __restrict__ w1b,
        const float* __restrict__ w2b,
        ushort* __restrict__ w1p, float* __restrict__ dproj) {
    const int t = threadIdx.x;
    if (blockIdx.x < 64) {
        __shared__ __align__(16) ushort tile[64 * 72];
        const int u0 = (blockIdx.x & 7) * 64;
        const int kc = blockIdx.x >> 3;
        const int ul = t & 63;
        const int db = t >> 6;
#pragma unroll
        for (int i = 0; i < 16; ++i) {
            const int d = db + i * 4;
            tile[ul * 72 + d] = f2bf(w1[(size_t)(kc * 64 + d) * UU + u0 + ul]);
        }
        __syncthreads();
        const int u = t >> 2;
        const int s = (t & 3) * 2;
        const int x = u & 7;
        short8 v0 = *(const short8*)&tile[u * 72 + s * 8];
        short8 v1 = *(const short8*)&tile[u * 72 + s * 8 + 8];
        *(short8*)&w1p[(size_t)kc * 32768 + (u0 + u) * 64 + (( s      ^ x)) * 8] = v0;
        *(short8*)&w1p[(size_t)kc * 32768 + (u0 + u) * 64 + (((s + 1) ^ x)) * 8] = v1;
    } else {
        const int g = blockIdx.x - 64;
        const int b = g >> 1;
        const int u = (g & 1) * 256 + t;
        float acc = 0.f;
#pragma unroll 8
        for (int d = 0; d < DD; ++d)
            acc += dec[b * DD + d] * w2[(size_t)d * UU + u];
        dproj[b * UU + u] = acc + w1b[u] + w2b[u];
    }
}

// ---------------- kernel 1: fused score GEMM (u-split halves) --------------
// scorep[half][m] = sum_{u in half} V_w[u] * tanh( enc[m]@W1[:,u] + dproj[b][u] )
// Block: 64 m-rows x 256 u, K-step 64, 4 waves. LDS 40 KB -> ~4 blocks/CU.
__global__ __launch_bounds__(256, 4) void score_kernel(
        const float* __restrict__ enc, const ushort* __restrict__ w1p,
        const float* __restrict__ dproj, const float* __restrict__ vw,
        float* __restrict__ scorep) {
    __shared__ __align__(16) ushort Bb[BN * BK];   // 32 KB
    __shared__ __align__(16) ushort Ab[BM * BK];   // 8 KB

    const int tid  = threadIdx.x;
    const int lane = tid & 63;
    const int wave = tid >> 6;               // u-chunk 0..3 (64 u each)
    const int mbase = blockIdx.x * BM;
    const int half  = blockIdx.y;            // u-half 0..1
    const int b = mbase / ROWS_PER_B;

    const int lrow = lane & 15;
    const int kgrp = lane >> 4;

    // A staging: thread -> (row = tid>>2, 16 floats = 2 swizzled 8-chunks)
    const int ar  = tid >> 2;                // 0..63
    const int ac  = (tid & 3) * 2;           // 0,2,4,6
    const float* abase = enc + (size_t)(mbase + ar) * DD + ac * 8;
    const int s0p = ( ac      ^ (ar & 7)) * 8;
    const int s1p = ((ac + 1) ^ (ar & 7)) * 8;
    const ushort* bsrc0 = w1p + half * 16384 + tid * 8;

    f32x4 acc[4][4] = {};

    for (int kc = 0; kc < 8; ++kc) {
        // ---- stage phase ----
        const ushort* bsrc = bsrc0 + (size_t)kc * 32768;
#pragma unroll
        for (int i = 0; i < 8; ++i)
            gload_lds16(bsrc + i * 2048, &Bb[tid * 8 + i * 2048]);
        {
            const float* asrc = abase + kc * 64;
            float4 a0 = ((const float4*)asrc)[0];
            float4 a1 = ((const float4*)asrc)[1];
            float4 a2 = ((const float4*)asrc)[2];
            float4 a3 = ((const float4*)asrc)[3];
            short8 w0, w1v;
            ushort* p0 = (ushort*)&w0; ushort* p1 = (ushort*)&w1v;
            p0[0]=f2bf(a0.x); p0[1]=f2bf(a0.y); p0[2]=f2bf(a0.z); p0[3]=f2bf(a0.w);
            p0[4]=f2bf(a1.x); p0[5]=f2bf(a1.y); p0[6]=f2bf(a1.z); p0[7]=f2bf(a1.w);
            p1[0]=f2bf(a2.x); p1[1]=f2bf(a2.y); p1[2]=f2bf(a2.z); p1[3]=f2bf(a2.w);
            p1[4]=f2bf(a3.x); p1[5]=f2bf(a3.y); p1[6]=f2bf(a3.z); p1[7]=f2bf(a3.w);
            *(short8*)&Ab[ar * 64 + s0p] = w0;
            *(short8*)&Ab[ar * 64 + s1p] = w1v;
        }
        __syncthreads();                     // staging visible

        // ---- compute phase ----
#pragma unroll
        for (int kk = 0; kk < 2; ++kk) {
            const int sub = kk * 4 + kgrp;
            short8 afr[4], bfr[4];
#pragma unroll
            for (int ms = 0; ms < 4; ++ms) {
                const int r = ms * 16 + lrow;
                afr[ms] = *(const short8*)&Ab[r * 64 + (sub ^ (r & 7)) * 8];
            }
#pragma unroll
            for (int uf = 0; uf < 4; ++uf) {
                const int u = wave * 64 + uf * 16 + lrow;
                bfr[uf] = *(const short8*)&Bb[u * 64 + (sub ^ (u & 7)) * 8];
            }
#pragma unroll
            for (int ms = 0; ms < 4; ++ms)
#pragma unroll
                for (int uf = 0; uf < 4; ++uf)
                    acc[ms][uf] = __builtin_amdgcn_mfma_f32_16x16x32_bf16(
                        afr[ms], bfr[uf], acc[ms][uf], 0, 0, 0);
        }
        __syncthreads();                     // compute done before overwrite
    }

    // ---- epilogue: + dec_proj, tanh, dot V_w, reduce ----
    float part[4][4] = {};
#pragma unroll
    for (int uf = 0; uf < 4; ++uf) {
        const int u = half * 256 + wave * 64 + uf * 16 + lrow;
        const float cadd = dproj[b * UU + u];
        const float vwe  = vw[u];
#pragma unroll
        for (int ms = 0; ms < 4; ++ms)
#pragma unroll
            for (int j = 0; j < 4; ++j) {
                float x = acc[ms][uf][j] + cadd;
                x = fminf(fmaxf(x, -15.f), 15.f);
                float e = __expf(2.f * x);
                part[ms][j] += vwe * ((e - 1.f) / (e + 1.f));
            }
    }
#pragma unroll
    for (int off = 1; off < 16; off <<= 1)
#pragma unroll
        for (int ms = 0; ms < 4; ++ms)
#pragma unroll
            for (int j = 0; j < 4; ++j)
                part[ms][j] += __shfl_xor(part[ms][j], off, 64);

    float* scr = (float*)&Ab[0];             // 1 KB scratch
    if (lrow == 0) {
#pragma unroll
        for (int ms = 0; ms < 4; ++ms)
#pragma unroll
            for (int j = 0; j < 4; ++j)
                scr[wave * 64 + ms * 16 + kgrp * 4 + j] = part[ms][j];
    }
    __syncthreads();
    if (tid < 64)
        scorep[(size_t)half * MTOT + mbase + tid] =
            scr[tid] + scr[64 + tid] + scr[128 + tid] + scr[192 + tid];
}

// ---------------- kernel 2: fused softmax + context partial ----------------
// grid (4, B): block (q, b). Sum the two u-half score partials + V_b, softmax
// over H per (b,w) in LDS, write this quarter's attn rows, accumulate a
// 192-row context partial per row-phase r0 (16 partial slices per b).
__global__ __launch_bounds__(512) void ctx_kernel(
        const float* __restrict__ scorep, const float* __restrict__ enc,
        const float* __restrict__ vb,
        float* __restrict__ attn, float* __restrict__ partial) {
    __shared__ float sl[ROWS_PER_B];
    __shared__ float al[ROWS_PER_B];
    const int q = blockIdx.x;
    const int b = blockIdx.y;
    const int t = threadIdx.x;

    const float vbv = vb[0];
    for (int i = t; i < ROWS_PER_B; i += 512)
        sl[i] = scorep[b * ROWS_PER_B + i] + scorep[MTOT + b * ROWS_PER_B + i] + vbv;
    __syncthreads();

    if (t < WWW) {
        float v[HHH];
        float m = -1e30f;
#pragma unroll
        for (int h = 0; h < HHH; ++h) { v[h] = sl[h * WWW + t]; m = fmaxf(m, v[h]); }
        float sum = 0.f;
#pragma unroll
        for (int h = 0; h < HHH; ++h) { v[h] = __expf(v[h] - m); sum += v[h]; }
        const float inv = 1.f / sum;
#pragma unroll
        for (int h = 0; h < HHH; ++h) al[h * WWW + t] = v[h] * inv;
    }
    __syncthreads();

    const int rb = q * 192;
    for (int i = t; i < 192; i += 512)
        attn[b * ROWS_PER_B + rb + i] = al[rb + i];

    const int r0 = t >> 7;                   // 0..3 row phase
    const int d4 = (t & 127) * 4;
    float4 acc = {0.f, 0.f, 0.f, 0.f};
    const float* ebase = enc + ((size_t)b * ROWS_PER_B + rb) * DD + d4;
#pragma unroll 8
    for (int i = 0; i < 48; ++i) {
        const int r = r0 + i * 4;
        const float a = al[rb + r];
        const float4 e = *(const float4*)(ebase + (size_t)r * DD);
        acc.x += a * e.x; acc.y += a * e.y; acc.z += a * e.z; acc.w += a * e.w;
    }
    *(float4*)(partial + ((size_t)((b * 4 + q) * 4 + r0)) * DD + d4) = acc;
}

// ---------------- kernel 3: reduce 16 partials -----------------------------
__global__ void ctx_reduce_kernel(const float* __restrict__ partial,
                                  float* __restrict__ out) {
    const int qd = blockIdx.x * 256 + threadIdx.x;   // 16384 quads
    const int b = qd >> 7;
    const int d4 = (qd & 127) * 4;
    float4 s = {0.f, 0.f, 0.f, 0.f};
#pragma unroll
    for (int j = 0; j < 16; ++j) {
        const float4 p = *(const float4*)(partial + ((size_t)(b * 16 + j)) * DD + d4);
        s.x += p.x; s.y += p.y; s.z += p.z; s.w += p.w;
    }
    *(float4*)(out + (size_t)b * DD + d4) = s;
}

extern "C" void kernel_launch(void* const* d_in, const int* in_sizes, int n_in,
                              void* d_out, int out_size, void* d_ws, size_t ws_size,
                              hipStream_t stream) {
    const float* dec = (const float*)d_in[0];
    const float* enc = (const float*)d_in[1];
    const float* w1w = (const float*)d_in[2];
    const float* w1b = (const float*)d_in[3];
    const float* w2w = (const float*)d_in[4];
    const float* w2b = (const float*)d_in[5];
    const float* vw  = (const float*)d_in[6];
    const float* vb  = (const float*)d_in[7];

    float* out = (float*)d_out;
    char* ws = (char*)d_ws;
    ushort* w1p    = (ushort*)(ws);                      // 512 KB
    float* dproj   = (float*)(ws + (512 << 10));         // 256 KB
    float* scorep  = (float*)(ws + (768 << 10));         // 768 KB (2 halves)
    float* partial = (float*)(ws + (1536 << 10));        // 4 MB (16 slices/b)

    float* ctx  = out;                 // (B, D)     = 65536 floats
    float* attn = out + BB * DD;       // (B,H,W,1)  = 98304 floats

    prep_kernel<<<320, 256, 0, stream>>>(w1w, dec, w2w, w1b, w2b, w1p, dproj);
    score_kernel<<<dim3(MTOT / BM, 2), 256, 0, stream>>>(enc, w1p, dproj, vw, scorep);
    ctx_kernel<<<dim3(4, BB), 512, 0, stream>>>(scorep, enc, vb, attn, partial);
    ctx_reduce_kernel<<<64, 256, 0, stream>>>(partial, ctx);
}